// Round 5
// baseline (754.448 us; speedup 1.0000x reference)
//
#include <hip/hip_runtime.h>

#define T_LEN 2048
#define HID   25
#define LOG2E 1.4426950408889634f

// may_alias vector for the LDS h-row readback (written as scalar float):
// without it, TBAA licenses hoisting the read above the publish (R3/R7 bug).
typedef float vf4 __attribute__((vector_size(16), may_alias));
typedef float f2  __attribute__((ext_vector_type(2)));

__device__ __forceinline__ float fast_rcp(float x) { return __builtin_amdgcn_rcpf(x); }
__device__ __forceinline__ float fast_exp2(float x) { return __builtin_amdgcn_exp2f(x); }

// R16: software-pipelined TWO chains per wave, in-stream.
//
// Evidence chain: R14 (2 waves/SIMD) 703 cyc/step = 483 issue + 220 stall --
// sibling wave filled nothing. R15 (384-cyc phase skew) EXACTLY neutral ->
// HW co-scheduling will not hide this latency, skewed or not. So hide it
// in ONE wave's instruction stream: each wave owns chains A and B, both in
// the R14 full-wave gate-split layout (24 pk_fma/chain -- same per-chain
// issue as the 546us champion), alternating in program order:
//     dotA, actA, publishA+readbackA,  dotB, actB, publishB+readbackB
// Chain A's LDS readback is in flight during dotB+actB+pubB (~250 cyc);
// chain B's during next dotA+actA. actA's trans chain overlaps dotB's
// pure-VGPR pk_fmas (compiler fences constrain memory ops only, not
// register FMAs). Weights are SHARED between the chains (one register set).
// 1024 waves = 1 wave/SIMD, waves_per_eu(1,1) -> full VGPR budget (R8
// lesson); LDS demand per CU per step unchanged vs champion (4 waves/CU).
//
// Per-chain numerics are exactly R14's (passed, absmax 1.953e-3):
//   lanes  0..24 own gates (i, g): p = sig(i)*tanh(g)   (all local)
//   lanes 32..56 own gates (f, o): c = fma(sig(f), c, p); h = sig(o)*tanh(c)
//   p crosses via __shfl_xor(p,32,64); same (k,k+12) pk-pairing, same
//   acc.x + fmaf(h24,...) tail, same exp2-domain activations, same y-dot.

__global__ __attribute__((amdgpu_flat_work_group_size(256, 256),
                          amdgpu_waves_per_eu(1, 1)))
void lstm_fused(
    const float* __restrict__ x,        // [B, T, 1]
    const float* __restrict__ w_ih,     // [100, 1]
    const float* __restrict__ w_hh,     // [100, 25]
    const float* __restrict__ b_ih,     // [100]
    const float* __restrict__ b_hh,     // [100]
    const float* __restrict__ w_dense,  // [1, 25]
    const float* __restrict__ b_dense,  // [1]
    float* __restrict__ out)            // [B, T, 1]
{
    const int tid = threadIdx.x;
    const int l   = tid & 63;            // lane in wave
    const int u   = l & 31;              // unit slot within half
    const int hh  = l >> 5;              // 0 -> gates (i,g); 1 -> gates (f,o)
    const int w   = tid >> 6;            // wave index in block, 0..3
    const int cb0 = (blockIdx.x * 4 + w) * 2;  // chains A = cb0, B = cb0+1
    const bool act = u < HID;

    // Broadcast rows: per wave, per chain, 64 slots (bijection; see R14).
    __shared__ __align__(16) float hbuf[4][2][64];
    // h history for batched y: per wave, per chain, 64 steps x 65 floats
    // (odd stride -> lane-strided y reads conflict-free).
    __shared__ float hist[4][2][64][65];   // 133 KB; + hbuf = 132 KB/block

    const float si = -LOG2E, sg = 2.f * LOG2E;

    // This lane's two gate rows (shared by both chains):
    //   lower: rowA = u     (i, scale si), rowB = 2*HID+u (g, scale sg)
    //   upper: rowA = HID+u (f, scale si), rowB = 3*HID+u (o, scale si)
    const int   rowA = hh ? (HID + u)     : u;
    const int   rowB = hh ? (3 * HID + u) : (2 * HID + u);
    const float scB  = hh ? si : sg;

    // ---- recurrent weights as (k, k+12) pairs, pre-scaled into exp2 domain ----
    f2 wA2[12], wB2[12];
#pragma unroll
    for (int m = 0; m < 12; ++m) {
        wA2[m] = act ? f2{si  * w_hh[rowA * HID + m], si  * w_hh[rowA * HID + m + 12]} : f2{0.f, 0.f};
        wB2[m] = act ? f2{scB * w_hh[rowB * HID + m], scB * w_hh[rowB * HID + m + 12]} : f2{0.f, 0.f};
    }
    const float wA24 = act ? si  * w_hh[rowA * HID + 24] : 0.f;
    const float wB24 = act ? scB * w_hh[rowB * HID + 24] : 0.f;
    const float bA   = act ? si  * (b_ih[rowA] + b_hh[rowA]) : 0.f;
    const float bB   = act ? scB * (b_ih[rowB] + b_hh[rowB]) : 0.f;
    const float wxA  = act ? si  * w_ih[rowA] : 0.f;
    const float wxB  = act ? scB * w_ih[rowB] : 0.f;
    const float bd   = b_dense[0];

    // dense weights (wave-uniform loads -> SGPRs)
    float wdv[HID];
#pragma unroll
    for (int i = 0; i < HID; ++i) wdv[i] = w_dense[i];

    // h0 = 0 (both chains, all 64 slots)
    hbuf[w][0][l] = 0.f;
    hbuf[w][1][l] = 0.f;

    // publish slot: full-wave bijection (upper active -> interleaved 0..24,
    // upper junk -> 25..31, lower -> 32..63). 64 distinct slots, 2 lanes/bank.
    const int slot = hh ? ((u < 12) ? 2 * u : (u < 24) ? 2 * u - 23 : u)
                        : (l + 32);
    // hist column: upper writes u (real for u<25), lower parks at 32+l.
    const int hcol = hh ? u : (32 + l);

    float* hwrA = &hbuf[w][0][slot];
    float* hwrB = &hbuf[w][1][slot];
    const vf4* r4A = (const vf4*)&hbuf[w][0][0];
    const vf4* r4B = (const vf4*)&hbuf[w][1][0];
    const float* hbFA = &hbuf[w][0][0];
    const float* hbFB = &hbuf[w][1][0];
    float (*histA)[65] = hist[w][0];
    float (*histB)[65] = hist[w][1];

    const float4* __restrict__ xpA = (const float4*)(x + (size_t)cb0 * T_LEN);
    const float4* __restrict__ xpB = (const float4*)(x + (size_t)(cb0 + 1) * T_LEN);
    float* __restrict__ orowA = out + (size_t)cb0 * T_LEN;
    float* __restrict__ orowB = out + (size_t)(cb0 + 1) * T_LEN;

    // h state as 12 register-aligned pairs (h_m, h_{m+12}) + h24, per chain
    f2 hpA[12], hpB[12];
#pragma unroll
    for (int m = 0; m < 12; ++m) { hpA[m] = f2{0.f, 0.f}; hpB[m] = f2{0.f, 0.f}; }
    float h24A = 0.f, h24B = 0.f;
    float cA = 0.f, cB = 0.f;

    float4 xcurA = xpA[0], xcurB = xpB[0];

    // One full LSTM step for one chain (R14's exact op order).
    auto step = [&](f2* hp, float& h24, float& c, float xv, int t,
                    float* hwr, const vf4* r4, const float* hbF,
                    float (*histc)[65], float* __restrict__ orow) {
        f2 accA = f2{fmaf(xv, wxA, bA), 0.f};
        f2 accB = f2{fmaf(xv, wxB, bB), 0.f};
#pragma unroll
        for (int m = 0; m < 12; ++m) {
            const f2 h = hp[m];
            accA = __builtin_elementwise_fma(h, wA2[m], accA);
            accB = __builtin_elementwise_fma(h, wB2[m], accB);
        }
        const float aA = accA.x + fmaf(h24, wA24, accA.y);
        const float aB = accB.x + fmaf(h24, wB24, accB.y);

        // lower: rA = sig(i), tB = tanh(g);  upper: rA = sig(f), rB = sig(o)
        const float rA = fast_rcp(1.f + fast_exp2(aA));
        const float rB = fast_rcp(1.f + fast_exp2(aB));
        const float tB = fmaf(-2.f, rB, 1.f);

        const float p  = rA * tB;                // lower: sig(i)*tanh(g)
        const float pX = __shfl_xor(p, 32, 64);  // partner's p (exact move)

        c = fmaf(rA, c, pX);                     // upper: fma(sig(f), c, sI*tG)
        const float tC = fmaf(-2.f, fast_rcp(1.f + fast_exp2(2.f * LOG2E * c)), 1.f);
        const float hn = rB * tC;                // upper: sig(o)*tanh(c)

        // ---- ordered publish -> readback (fences compile-time only;
        // same-wave DS ops execute in order on HW) ----
        *hwr = hn;                        // bijection slot (upper = real h)
        histc[t & 63][hcol] = hn;         // upper -> cols 0..24 real
        __asm__ __volatile__("" ::: "memory");
        {
            vf4 a0 = r4[0], a1 = r4[1], a2 = r4[2];
            vf4 a3 = r4[3], a4 = r4[4], a5 = r4[5];
            hp[0]  = f2{a0[0], a0[1]}; hp[1]  = f2{a0[2], a0[3]};
            hp[2]  = f2{a1[0], a1[1]}; hp[3]  = f2{a1[2], a1[3]};
            hp[4]  = f2{a2[0], a2[1]}; hp[5]  = f2{a2[2], a2[3]};
            hp[6]  = f2{a3[0], a3[1]}; hp[7]  = f2{a3[2], a3[3]};
            hp[8]  = f2{a4[0], a4[1]}; hp[9]  = f2{a4[2], a4[3]};
            hp[10] = f2{a5[0], a5[1]}; hp[11] = f2{a5[2], a5[3]};
            h24 = hbF[24];
        }
        __asm__ __volatile__("" ::: "memory");

        // batched y: every 64 steps lane l computes y[t0+l] (full 25-sum,
        // hist reads conflict-free by stride-65), all 64 lanes store.
        if ((t & 63) == 63) {
            const float* hrow = &histc[l][0];   // row for t' = t0 + l
            float ys = 0.f;
#pragma unroll
            for (int i = 0; i < HID; ++i)
                ys = fmaf(hrow[i], wdv[i], ys);
            orow[(t & ~63) + l] = ys + bd;      // 256 B coalesced
        }
    };

    for (int it = 0; it < T_LEN / 4; ++it) {
        const int nx = (it + 1 < T_LEN / 4) ? it + 1 : it;
        float4 xnA = xpA[nx], xnB = xpB[nx];    // issued ~4 steps ahead of use
        float xsA[4] = {xcurA.x, xcurA.y, xcurA.z, xcurA.w};
        float xsB[4] = {xcurB.x, xcurB.y, xcurB.z, xcurB.w};

#pragma unroll
        for (int s = 0; s < 4; ++s) {
            const int t = 4 * it + s;
            // Chain A step: its readback (issued below) flies during chain
            // B's dot+act+publish. Chain B's readback flies during the next
            // s-iteration's chain-A dot+act (in-stream, unrolled x4).
            step(hpA, h24A, cA, xsA[s], t, hwrA, r4A, hbFA, histA, orowA);
            step(hpB, h24B, cB, xsB[s], t, hwrB, r4B, hbFB, histB, orowB);
        }
        xcurA = xnA;
        xcurB = xnB;
    }
}

extern "C" void kernel_launch(void* const* d_in, const int* in_sizes, int n_in,
                              void* d_out, int out_size, void* d_ws, size_t ws_size,
                              hipStream_t stream) {
    const float* x       = (const float*)d_in[0];
    const float* w_ih    = (const float*)d_in[1];
    const float* w_hh    = (const float*)d_in[2];
    const float* b_ih    = (const float*)d_in[3];
    const float* b_hh    = (const float*)d_in[4];
    const float* w_dense = (const float*)d_in[5];
    const float* b_dense = (const float*)d_in[6];
    float* out = (float*)d_out;

    // 2048 chains, two per wave (in-stream pipelined): 256 blocks x 256
    // threads -> 1024 waves = 1 wave/SIMD chip-wide, 4 waves/CU, 1 block/CU
    // (132 KB LDS/block).
    lstm_fused<<<dim3(256), dim3(256), 0, stream>>>(x, w_ih, w_hh, b_ih, b_hh,
                                                    w_dense, b_dense, out);
}